// Round 7
// baseline (235.427 us; speedup 1.0000x reference)
//
#include <hip/hip_runtime.h>

// NT-Xent loss: z_i, z_j [4096,1024] f32 -> scalar f32 loss.
// loss = mean_i( log(sum_{j != i} exp(2*cos_sim(i,j))) - 2*cos_sim(i, i^1) )
//
// R7: MX-fp8 32x32x64 scaled MFMA kept; staging/LDS geometry reverted to the
//     R3/R5-proven bf16 pattern scaled to fp8: BK=128 bytes (8 x 16B chunks
//     per row), slot = r*8 + (c ^ (r&7)) (within-row permutation -> GLDS
//     coalesced 128-B windows, ds_read phase-wise 2-way = conflict-free).
//     128x128 tiles, 4 waves, LDS 64 KiB dbuf -> 2 blocks/CU. Triangle grid
//     2080 tiles (99% packing).

#define N_ROWS 8192
#define HALF_N 4096
#define DIMK   1024
#define BK     128         // fp8 bytes per K-step
#define KSTEPS (DIMK / BK) // 8
#define NPANEL 64          // 128-row panels
#define NTILES 2080        // 64*65/2
#define LOGIT_SCALE (2.0f / 256.0f)   // /TEMPERATURE, undo 16*16 fp8 pre-scale

typedef float        f32x16 __attribute__((ext_vector_type(16)));
typedef int          i32x8  __attribute__((ext_vector_type(8)));
typedef unsigned int u32x4  __attribute__((ext_vector_type(4)));

// ---------------- fp8 e4m3 (OCP) conversion, RNE, software ------------------
__device__ __forceinline__ unsigned int f32_to_e4m3(float f) {
    unsigned int b = __float_as_uint(f);
    unsigned int s = (b >> 24) & 0x80u;
    float a = fabsf(f);
    if (a < 0.0009765625f) return s;                  // < 2^-10 -> 0
    if (a < 0.015625f) {                              // subnormal: m * 2^-9
        int q = (int)rintf(a * 512.0f);               // 0..8 (8 -> min normal)
        return s | (unsigned int)q;
    }
    if (a >= 464.0f) return s | 0x7Eu;                // clamp to 448
    int e = (int)((b >> 23) & 0xFF) - 127;            // [-6, 8]
    unsigned int man = b & 0x7FFFFFu;
    unsigned int r = man + 0x7FFFFu + ((man >> 20) & 1u);  // RNE to 3 bits
    unsigned int m8 = r >> 20;
    if (m8 == 8u) { m8 = 0u; ++e; if (e > 8) return s | 0x7Eu; }
    return s | ((unsigned int)(e + 7) << 3) | m8;
}

// ---------------- Kernel 1: row L2-normalize, f32 -> fp8*16 ------------------
__global__ __launch_bounds__(256) void norm_rows_kernel(
    const float* __restrict__ z_i, const float* __restrict__ z_j,
    unsigned int* __restrict__ xn8)   // [8192][256] u32 (=1024 fp8)
{
    const int wave = threadIdx.x >> 6, lane = threadIdx.x & 63;
    const int row = blockIdx.x * 4 + wave;
    const float* src = (row < HALF_N) ? (z_i + (size_t)row * DIMK)
                                      : (z_j + (size_t)(row - HALF_N) * DIMK);
    float4 v[4];
    float ss = 0.0f;
    #pragma unroll
    for (int i = 0; i < 4; ++i) {
        v[i] = ((const float4*)src)[i * 64 + lane];
        ss += v[i].x * v[i].x + v[i].y * v[i].y + v[i].z * v[i].z + v[i].w * v[i].w;
    }
    #pragma unroll
    for (int m = 1; m < 64; m <<= 1) ss += __shfl_xor(ss, m, 64);
    const float rn = 16.0f / fmaxf(sqrtf(ss), 1e-8f);   // x16 fp8 pre-scale

    unsigned int* dst = xn8 + (size_t)row * (DIMK / 4);
    #pragma unroll
    for (int i = 0; i < 4; ++i) {
        unsigned int p = f32_to_e4m3(v[i].x * rn)
                       | (f32_to_e4m3(v[i].y * rn) << 8)
                       | (f32_to_e4m3(v[i].z * rn) << 16)
                       | (f32_to_e4m3(v[i].w * rn) << 24);
        dst[i * 64 + lane] = p;
    }
}

// ---- Kernel 2: fused sim-GEMM (MX-fp8 32x32x64) + exp row/col sums ----------
#define BAR() do { asm volatile("" ::: "memory"); \
                   __builtin_amdgcn_s_barrier();  \
                   asm volatile("" ::: "memory"); } while (0)
#define WAITVM0() asm volatile("s_waitcnt vmcnt(0)" ::: "memory")
#define GLDS(gp, lp) __builtin_amdgcn_global_load_lds(                          \
        (const __attribute__((address_space(1))) void*)(gp),                    \
        (__attribute__((address_space(3))) void*)(lp), 16, 0, 0)

__global__ __launch_bounds__(256, 2) void simexp_kernel(
    const unsigned char* __restrict__ xn8,
    float* __restrict__ rs,     // [128][N_ROWS] plane jp*2 + wn
    float* __restrict__ cs,     // [128][N_ROWS] plane ip*2 + wm
    float* __restrict__ tgt)    // [N_ROWS]
{
    __shared__ u32x4 Abuf[2][1024];   // 2 x 16 KiB: 128 rows x 8 chunks of 16B
    __shared__ u32x4 Bbuf[2][1024];

    // bijective XCD swizzle: 2080 = 8 * 260
    const int orig = blockIdx.x;
    const int bid  = (orig & 7) * 260 + (orig >> 3);

    // decode (ip, jp), ip <= jp
    int rem = bid, ip = 0;
    while (rem >= NPANEL - ip) { rem -= NPANEL - ip; ++ip; }
    const int jp = ip + rem;
    const bool diag = (ip == jp);

    const int t = threadIdx.x;
    const int lane = t & 63, wave = t >> 6;
    const int wm = wave >> 1, wn = wave & 1;     // 2x2 wave grid, 64x64 each
    const int rowBase = ip * 128, colBase = jp * 128;
    const int l31 = lane & 31, h = lane >> 5;

    f32x16 acc[2][2];
    #pragma unroll
    for (int i = 0; i < 2; ++i)
        #pragma unroll
        for (int j = 0; j < 2; ++j)
            #pragma unroll
            for (int v = 0; v < 16; ++v) acc[i][j][v] = 0.0f;

    // staging: unit u = p*256 + t; row r = u>>3, stored chunk u&7,
    // global chunk c = (u&7) ^ (r&7)  (within-row perm -> 128B coalesced)
    const int r_st = t >> 3;                       // 0..31 (+p*32)
    const int c_st = (t & 7);

#define STAGE_TILE(SLOT, KT) do {                                                \
        _Pragma("unroll")                                                        \
        for (int p_ = 0; p_ < 4; ++p_) {                                         \
            const int r_ = p_ * 32 + r_st;                                       \
            const int c_ = c_st ^ (r_ & 7);                                      \
            const unsigned char* gA = xn8 +                                      \
                (size_t)(rowBase + r_) * DIMK + (KT) * BK + c_ * 16;             \
            const unsigned char* gB = xn8 +                                      \
                (size_t)(colBase + r_) * DIMK + (KT) * BK + c_ * 16;             \
            GLDS(gA, &Abuf[SLOT][p_ * 256 + wave * 64]);                         \
            GLDS(gB, &Bbuf[SLOT][p_ * 256 + wave * 64]);                         \
        }                                                                        \
    } while (0)

    // prologue
    STAGE_TILE(0, 0);
    WAITVM0();
    BAR();

    int slot = 0;
    for (int kt = 0; kt < KSTEPS; ++kt) {
        const bool nx = (kt + 1 < KSTEPS);
        if (nx) STAGE_TILE(slot ^ 1, kt + 1);

        // frag reads: row = fragbase + l31, chunks ks*4 + 2h + {0,1}
        union Frag { u32x4 q[2]; i32x8 v; };
        i32x8 af[2][2], bf[2][2];
        #pragma unroll
        for (int fi = 0; fi < 2; ++fi) {
            const int r = wm * 64 + fi * 32 + l31;
            #pragma unroll
            for (int ks = 0; ks < 2; ++ks) {
                const int c0 = ks * 4 + 2 * h;
                Frag fa;
                fa.q[0] = Abuf[slot][r * 8 + (c0 ^ (r & 7))];
                fa.q[1] = Abuf[slot][r * 8 + ((c0 + 1) ^ (r & 7))];
                af[fi][ks] = fa.v;
            }
        }
        #pragma unroll
        for (int cf = 0; cf < 2; ++cf) {
            const int r = wn * 64 + cf * 32 + l31;
            #pragma unroll
            for (int ks = 0; ks < 2; ++ks) {
                const int c0 = ks * 4 + 2 * h;
                Frag fb;
                fb.q[0] = Bbuf[slot][r * 8 + (c0 ^ (r & 7))];
                fb.q[1] = Bbuf[slot][r * 8 + ((c0 + 1) ^ (r & 7))];
                bf[cf][ks] = fb.v;
            }
        }

        __builtin_amdgcn_s_setprio(1);
        #pragma unroll
        for (int fi = 0; fi < 2; ++fi)
            #pragma unroll
            for (int cf = 0; cf < 2; ++cf)
                #pragma unroll
                for (int ks = 0; ks < 2; ++ks)
                    acc[fi][cf] = __builtin_amdgcn_mfma_scale_f32_32x32x64_f8f6f4(
                        af[fi][ks], bf[cf][ks], acc[fi][cf], 0, 0,
                        0, 0x7F7F7F7F, 0, 0x7F7F7F7F);   // fmt=fp8, scales=1.0
        __builtin_amdgcn_s_setprio(0);

        if (nx) WAITVM0();
        BAR();
        slot ^= 1;
    }
#undef STAGE_TILE

    // ---- epilogue ----
    // C/D 32x32 layout (m74/m101): col = lane&31, row = (v&3)+8*(v>>2)+4*(lane>>5)
    float cspart[2] = {0.0f, 0.0f};
    #pragma unroll
    for (int fi = 0; fi < 2; ++fi) {
        float rpart[16];
        #pragma unroll
        for (int v = 0; v < 16; ++v) rpart[v] = 0.0f;
        #pragma unroll
        for (int cf = 0; cf < 2; ++cf) {
            const int gcol = colBase + wn * 64 + cf * 32 + l31;
            #pragma unroll
            for (int v = 0; v < 16; ++v) {
                const int grow = rowBase + wm * 64 + fi * 32
                               + (v & 3) + 8 * (v >> 2) + 4 * h;
                const float tv = acc[fi][cf][v] * LOGIT_SCALE;
                if (gcol == grow + 1 && ((grow & 1) == 0)) {
                    tgt[grow] = tv; tgt[grow + 1] = tv;   // sim symmetric
                }
                const float ev = (gcol == grow) ? 0.0f : __expf(tv);
                rpart[v] += ev;
                cspart[cf] += ev;
            }
        }
        // row sums: reduce over 32 columns (l31); h-halves hold disjoint rows
        #pragma unroll
        for (int m = 1; m < 32; m <<= 1) {
            #pragma unroll
            for (int v = 0; v < 16; ++v) rpart[v] += __shfl_xor(rpart[v], m, 64);
        }
        if (l31 == 0) {
            float* dst = rs + (size_t)(jp * 2 + wn) * N_ROWS;
            #pragma unroll
            for (int v = 0; v < 16; ++v)
                dst[rowBase + wm * 64 + fi * 32 + (v & 3) + 8 * (v >> 2) + 4 * h]
                    = rpart[v];
        }
    }
    if (!diag) {
        // mirrored column sums -> rows of panel jp, plane ip*2 + wm
        #pragma unroll
        for (int cf = 0; cf < 2; ++cf) {
            cspart[cf] += __shfl_xor(cspart[cf], 32, 64);
            if (lane < 32)
                cs[(size_t)(ip * 2 + wm) * N_ROWS
                   + colBase + wn * 64 + cf * 32 + l31] = cspart[cf];
        }
    }
}

// ------------- Kernel 3: per-row LSE - target logit --------------------------
// row r (panel P = r>>7): rs planes jp*2+{0,1} for jp >= P (tiles (P,jp)),
// cs planes ip*2+{0,1} for ip < P (tiles (ip,P), mirrored).
__global__ __launch_bounds__(256) void row_term_kernel(
    const float* __restrict__ rs, const float* __restrict__ cs,
    const float* __restrict__ tgt, float* __restrict__ terms)
{
    const int row = blockIdx.x * 256 + threadIdx.x;
    const int P = row >> 7;
    float s = 0.0f;
    for (int jp = P; jp < NPANEL; ++jp) {
        const float* b = rs + (size_t)(jp * 2) * N_ROWS + row;
        s += b[0] + b[N_ROWS];
    }
    for (int ipp = 0; ipp < P; ++ipp) {
        const float* b = cs + (size_t)(ipp * 2) * N_ROWS + row;
        s += b[0] + b[N_ROWS];
    }
    terms[row] = logf(s) - tgt[row];
}

// ------------- Kernel 4: mean over rows --------------------------------------
__global__ __launch_bounds__(256) void loss_kernel(
    const float* __restrict__ terms, float* __restrict__ out)
{
    const int t = threadIdx.x;
    float s = 0.0f;
    for (int i = t; i < N_ROWS; i += 256) s += terms[i];
    #pragma unroll
    for (int m = 1; m < 64; m <<= 1) s += __shfl_xor(s, m, 64);
    __shared__ float red[4];
    if ((t & 63) == 0) red[t >> 6] = s;
    __syncthreads();
    if (t == 0) out[0] = (red[0] + red[1] + red[2] + red[3]) * (1.0f / N_ROWS);
}

extern "C" void kernel_launch(void* const* d_in, const int* in_sizes, int n_in,
                              void* d_out, int out_size, void* d_ws, size_t ws_size,
                              hipStream_t stream)
{
    const float* z_i = (const float*)d_in[0];
    const float* z_j = (const float*)d_in[1];
    float* out = (float*)d_out;

    // workspace layout
    unsigned char* xn8 = (unsigned char*)d_ws;                        // 8 MiB fp8
    float* rs    = (float*)(xn8 + (size_t)N_ROWS * DIMK);             // 4 MiB
    float* cs    = rs + (size_t)128 * N_ROWS;                         // 4 MiB
    float* tgt   = cs + (size_t)128 * N_ROWS;                         // 32 KiB
    float* terms = tgt + N_ROWS;                                      // 32 KiB

    norm_rows_kernel<<<N_ROWS / 4, 256, 0, stream>>>(z_i, z_j, (unsigned int*)xn8);
    simexp_kernel<<<NTILES, 256, 0, stream>>>(xn8, rs, cs, tgt);
    row_term_kernel<<<N_ROWS / 256, 256, 0, stream>>>(rs, cs, tgt, terms);
    loss_kernel<<<1, 256, 0, stream>>>(terms, out);
}

// Round 8
// 229.912 us; speedup vs baseline: 1.0240x; 1.0240x over previous
//
#include <hip/hip_runtime.h>

// NT-Xent loss: z_i, z_j [4096,1024] f32 -> scalar f32 loss.
// loss = mean_i( log(sum_{j != i} exp(2*cos_sim(i,j))) - 2*cos_sim(i, i^1) )
//
// R8: R7 geometry (MX-fp8 32x32x64, 128^2 triangle tiles, BK=128, 2 blk/CU)
//     with ALL fragment/accumulator state in NAMED variables (no arrays, no
//     unions) to kill the R7 scratch spill (rule #20). Frag pairs combined
//     via __builtin_shufflevector (register concat).

#define N_ROWS 8192
#define HALF_N 4096
#define DIMK   1024
#define BK     128         // fp8 bytes per K-step
#define KSTEPS (DIMK / BK) // 8
#define NPANEL 64          // 128-row panels
#define NTILES 2080        // 64*65/2
#define LOGIT_SCALE (2.0f / 256.0f)   // /TEMPERATURE, undo 16*16 fp8 pre-scale

typedef float        f32x16 __attribute__((ext_vector_type(16)));
typedef int          i32x8  __attribute__((ext_vector_type(8)));
typedef unsigned int u32x4  __attribute__((ext_vector_type(4)));
typedef unsigned int u32x8  __attribute__((ext_vector_type(8)));

// ---------------- fp8 e4m3 (OCP) conversion, RNE, software ------------------
__device__ __forceinline__ unsigned int f32_to_e4m3(float f) {
    unsigned int b = __float_as_uint(f);
    unsigned int s = (b >> 24) & 0x80u;
    float a = fabsf(f);
    if (a < 0.0009765625f) return s;                  // < 2^-10 -> 0
    if (a < 0.015625f) {                              // subnormal: m * 2^-9
        int q = (int)rintf(a * 512.0f);               // 0..8 (8 -> min normal)
        return s | (unsigned int)q;
    }
    if (a >= 464.0f) return s | 0x7Eu;                // clamp to 448
    int e = (int)((b >> 23) & 0xFF) - 127;            // [-6, 8]
    unsigned int man = b & 0x7FFFFFu;
    unsigned int r = man + 0x7FFFFu + ((man >> 20) & 1u);  // RNE to 3 bits
    unsigned int m8 = r >> 20;
    if (m8 == 8u) { m8 = 0u; ++e; if (e > 8) return s | 0x7Eu; }
    return s | ((unsigned int)(e + 7) << 3) | m8;
}

// ---------------- Kernel 1: row L2-normalize, f32 -> fp8*16 ------------------
__global__ __launch_bounds__(256) void norm_rows_kernel(
    const float* __restrict__ z_i, const float* __restrict__ z_j,
    unsigned int* __restrict__ xn8)   // [8192][256] u32 (=1024 fp8)
{
    const int wave = threadIdx.x >> 6, lane = threadIdx.x & 63;
    const int row = blockIdx.x * 4 + wave;
    const float* src = (row < HALF_N) ? (z_i + (size_t)row * DIMK)
                                      : (z_j + (size_t)(row - HALF_N) * DIMK);
    float4 v0 = ((const float4*)src)[0 * 64 + lane];
    float4 v1 = ((const float4*)src)[1 * 64 + lane];
    float4 v2 = ((const float4*)src)[2 * 64 + lane];
    float4 v3 = ((const float4*)src)[3 * 64 + lane];
    float ss = v0.x*v0.x + v0.y*v0.y + v0.z*v0.z + v0.w*v0.w
             + v1.x*v1.x + v1.y*v1.y + v1.z*v1.z + v1.w*v1.w
             + v2.x*v2.x + v2.y*v2.y + v2.z*v2.z + v2.w*v2.w
             + v3.x*v3.x + v3.y*v3.y + v3.z*v3.z + v3.w*v3.w;
    #pragma unroll
    for (int m = 1; m < 64; m <<= 1) ss += __shfl_xor(ss, m, 64);
    const float rn = 16.0f / fmaxf(sqrtf(ss), 1e-8f);   // x16 fp8 pre-scale

    unsigned int* dst = xn8 + (size_t)row * (DIMK / 4);
#define PACK4(V) (f32_to_e4m3((V).x * rn) | (f32_to_e4m3((V).y * rn) << 8) | \
                  (f32_to_e4m3((V).z * rn) << 16) | (f32_to_e4m3((V).w * rn) << 24))
    dst[0 * 64 + lane] = PACK4(v0);
    dst[1 * 64 + lane] = PACK4(v1);
    dst[2 * 64 + lane] = PACK4(v2);
    dst[3 * 64 + lane] = PACK4(v3);
#undef PACK4
}

// ---- Kernel 2: fused sim-GEMM (MX-fp8 32x32x64) + exp row/col sums ----------
#define BAR() do { asm volatile("" ::: "memory"); \
                   __builtin_amdgcn_s_barrier();  \
                   asm volatile("" ::: "memory"); } while (0)
#define WAITVM0() asm volatile("s_waitcnt vmcnt(0)" ::: "memory")
#define GLDS(gp, lp) __builtin_amdgcn_global_load_lds(                          \
        (const __attribute__((address_space(1))) void*)(gp),                    \
        (__attribute__((address_space(3))) void*)(lp), 16, 0, 0)

// frag load: two 16B LDS units (XOR-swizzled within row) -> one i32x8
__device__ __forceinline__ i32x8 ldfrag8(const u32x4* __restrict__ buf,
                                         int r, int c0) {
    const u32x4 lo = buf[r * 8 + ((c0)     ^ (r & 7))];
    const u32x4 hi = buf[r * 8 + ((c0 + 1) ^ (r & 7))];
    return __builtin_bit_cast(i32x8,
        __builtin_shufflevector(lo, hi, 0, 1, 2, 3, 4, 5, 6, 7));
}

__global__ __launch_bounds__(256, 2) void simexp_kernel(
    const unsigned char* __restrict__ xn8,
    float* __restrict__ rs,     // [128][N_ROWS] plane jp*2 + wn
    float* __restrict__ cs,     // [128][N_ROWS] plane ip*2 + wm
    float* __restrict__ tgt)    // [N_ROWS]
{
    __shared__ u32x4 Abuf[2][1024];   // 2 x 16 KiB: 128 rows x 8 chunks of 16B
    __shared__ u32x4 Bbuf[2][1024];

    // bijective XCD swizzle: 2080 = 8 * 260
    const int orig = blockIdx.x;
    const int bid  = (orig & 7) * 260 + (orig >> 3);

    // decode (ip, jp), ip <= jp
    int rem = bid, ip = 0;
    while (rem >= NPANEL - ip) { rem -= NPANEL - ip; ++ip; }
    const int jp = ip + rem;
    const bool diag = (ip == jp);

    const int t = threadIdx.x;
    const int lane = t & 63, wave = t >> 6;
    const int wm = wave >> 1, wn = wave & 1;     // 2x2 wave grid, 64x64 each
    const int rowBase = ip * 128, colBase = jp * 128;
    const int l31 = lane & 31, h = lane >> 5;

    f32x16 acc00, acc01, acc10, acc11;
    #pragma unroll
    for (int v = 0; v < 16; ++v) {
        acc00[v] = 0.0f; acc01[v] = 0.0f; acc10[v] = 0.0f; acc11[v] = 0.0f;
    }

    // staging: unit u = p*256 + t; row r = u>>3, stored chunk u&7,
    // global chunk c = (u&7) ^ (r&7)  (within-row perm -> 128B coalesced)
    const int r_st = t >> 3;                       // 0..31 (+p*32)
    const int c_st = (t & 7);

#define STAGE_TILE(SLOT, KT) do {                                                \
        _Pragma("unroll")                                                        \
        for (int p_ = 0; p_ < 4; ++p_) {                                         \
            const int r_ = p_ * 32 + r_st;                                       \
            const int c_ = c_st ^ (r_ & 7);                                      \
            const unsigned char* gA = xn8 +                                      \
                (size_t)(rowBase + r_) * DIMK + (KT) * BK + c_ * 16;             \
            const unsigned char* gB = xn8 +                                      \
                (size_t)(colBase + r_) * DIMK + (KT) * BK + c_ * 16;             \
            GLDS(gA, &Abuf[SLOT][p_ * 256 + wave * 64]);                         \
            GLDS(gB, &Bbuf[SLOT][p_ * 256 + wave * 64]);                         \
        }                                                                        \
    } while (0)

    // prologue
    STAGE_TILE(0, 0);
    WAITVM0();
    BAR();

    const int rA0 = wm * 64 + l31, rA1 = wm * 64 + 32 + l31;
    const int rB0 = wn * 64 + l31, rB1 = wn * 64 + 32 + l31;
    const int c0a = 2 * h;        // ks=0 chunk base
    const int c0b = 4 + 2 * h;    // ks=1 chunk base

    int slot = 0;
    for (int kt = 0; kt < KSTEPS; ++kt) {
        const bool nx = (kt + 1 < KSTEPS);
        if (nx) STAGE_TILE(slot ^ 1, kt + 1);

        const u32x4* __restrict__ Ap = &Abuf[slot][0];
        const u32x4* __restrict__ Bp = &Bbuf[slot][0];
        const i32x8 a0k0 = ldfrag8(Ap, rA0, c0a);
        const i32x8 a0k1 = ldfrag8(Ap, rA0, c0b);
        const i32x8 a1k0 = ldfrag8(Ap, rA1, c0a);
        const i32x8 a1k1 = ldfrag8(Ap, rA1, c0b);
        const i32x8 b0k0 = ldfrag8(Bp, rB0, c0a);
        const i32x8 b0k1 = ldfrag8(Bp, rB0, c0b);
        const i32x8 b1k0 = ldfrag8(Bp, rB1, c0a);
        const i32x8 b1k1 = ldfrag8(Bp, rB1, c0b);

        __builtin_amdgcn_s_setprio(1);
#define MM(ACC, A, B) ACC = __builtin_amdgcn_mfma_scale_f32_32x32x64_f8f6f4(     \
            (A), (B), ACC, 0, 0, 0, 0x7F7F7F7F, 0, 0x7F7F7F7F)
        MM(acc00, a0k0, b0k0); MM(acc00, a0k1, b0k1);
        MM(acc01, a0k0, b1k0); MM(acc01, a0k1, b1k1);
        MM(acc10, a1k0, b0k0); MM(acc10, a1k1, b0k1);
        MM(acc11, a1k0, b1k0); MM(acc11, a1k1, b1k1);
#undef MM
        __builtin_amdgcn_s_setprio(0);

        if (nx) WAITVM0();
        BAR();
        slot ^= 1;
    }
#undef STAGE_TILE

    // ---- epilogue ----
    // C/D 32x32 layout (m74/m101): col = lane&31, row = (v&3)+8*(v>>2)+4*(lane>>5)
    float cs0 = 0.0f, cs1 = 0.0f;
    float rpart[16];

#define HARVEST(ACC, FI, CF) do {                                                \
        const int gcol = colBase + wn * 64 + (CF) * 32 + l31;                    \
        _Pragma("unroll")                                                        \
        for (int v = 0; v < 16; ++v) {                                           \
            const int grow = rowBase + wm * 64 + (FI) * 32                       \
                           + (v & 3) + 8 * (v >> 2) + 4 * h;                     \
            const float tv = ACC[v] * LOGIT_SCALE;                               \
            if (gcol == grow + 1 && ((grow & 1) == 0)) {                         \
                tgt[grow] = tv; tgt[grow + 1] = tv;                              \
            }                                                                    \
            const float ev = (gcol == grow) ? 0.0f : __expf(tv);                 \
            rpart[v] += ev;                                                      \
            if (CF) cs1 += ev; else cs0 += ev;                                   \
        }                                                                        \
    } while (0)
#define REDUCE_STORE(FI) do {                                                    \
        _Pragma("unroll")                                                        \
        for (int m = 1; m < 32; m <<= 1) {                                       \
            _Pragma("unroll")                                                    \
            for (int v = 0; v < 16; ++v) rpart[v] += __shfl_xor(rpart[v], m, 64);\
        }                                                                        \
        if (l31 == 0) {                                                          \
            float* dst = rs + (size_t)(jp * 2 + wn) * N_ROWS;                    \
            _Pragma("unroll")                                                    \
            for (int v = 0; v < 16; ++v)                                         \
                dst[rowBase + wm * 64 + (FI) * 32                                \
                    + (v & 3) + 8 * (v >> 2) + 4 * h] = rpart[v];                \
        }                                                                        \
    } while (0)

    #pragma unroll
    for (int v = 0; v < 16; ++v) rpart[v] = 0.0f;
    HARVEST(acc00, 0, 0); HARVEST(acc01, 0, 1);
    REDUCE_STORE(0);
    #pragma unroll
    for (int v = 0; v < 16; ++v) rpart[v] = 0.0f;
    HARVEST(acc10, 1, 0); HARVEST(acc11, 1, 1);
    REDUCE_STORE(1);
#undef HARVEST
#undef REDUCE_STORE

    if (!diag) {
        // mirrored column sums -> rows of panel jp, plane ip*2 + wm
        cs0 += __shfl_xor(cs0, 32, 64);
        cs1 += __shfl_xor(cs1, 32, 64);
        if (lane < 32) {
            float* dst = cs + (size_t)(ip * 2 + wm) * N_ROWS + colBase + wn * 64;
            dst[l31]      = cs0;
            dst[32 + l31] = cs1;
        }
    }
}

// ------------- Kernel 3: per-row LSE - target logit --------------------------
// row r (panel P = r>>7): rs planes jp*2+{0,1} for jp >= P (tiles (P,jp)),
// cs planes ip*2+{0,1} for ip < P (tiles (ip,P), mirrored).
__global__ __launch_bounds__(256) void row_term_kernel(
    const float* __restrict__ rs, const float* __restrict__ cs,
    const float* __restrict__ tgt, float* __restrict__ terms)
{
    const int row = blockIdx.x * 256 + threadIdx.x;
    const int P = row >> 7;
    float s = 0.0f;
    for (int jp = P; jp < NPANEL; ++jp) {
        const float* b = rs + (size_t)(jp * 2) * N_ROWS + row;
        s += b[0] + b[N_ROWS];
    }
    for (int ipp = 0; ipp < P; ++ipp) {
        const float* b = cs + (size_t)(ipp * 2) * N_ROWS + row;
        s += b[0] + b[N_ROWS];
    }
    terms[row] = logf(s) - tgt[row];
}

// ------------- Kernel 4: mean over rows --------------------------------------
__global__ __launch_bounds__(256) void loss_kernel(
    const float* __restrict__ terms, float* __restrict__ out)
{
    const int t = threadIdx.x;
    float s = 0.0f;
    for (int i = t; i < N_ROWS; i += 256) s += terms[i];
    #pragma unroll
    for (int m = 1; m < 64; m <<= 1) s += __shfl_xor(s, m, 64);
    __shared__ float red[4];
    if ((t & 63) == 0) red[t >> 6] = s;
    __syncthreads();
    if (t == 0) out[0] = (red[0] + red[1] + red[2] + red[3]) * (1.0f / N_ROWS);
}

extern "C" void kernel_launch(void* const* d_in, const int* in_sizes, int n_in,
                              void* d_out, int out_size, void* d_ws, size_t ws_size,
                              hipStream_t stream)
{
    const float* z_i = (const float*)d_in[0];
    const float* z_j = (const float*)d_in[1];
    float* out = (float*)d_out;

    // workspace layout
    unsigned char* xn8 = (unsigned char*)d_ws;                        // 8 MiB fp8
    float* rs    = (float*)(xn8 + (size_t)N_ROWS * DIMK);             // 4 MiB
    float* cs    = rs + (size_t)128 * N_ROWS;                         // 4 MiB
    float* tgt   = cs + (size_t)128 * N_ROWS;                         // 32 KiB
    float* terms = tgt + N_ROWS;                                      // 32 KiB

    norm_rows_kernel<<<N_ROWS / 4, 256, 0, stream>>>(z_i, z_j, (unsigned int*)xn8);
    simexp_kernel<<<NTILES, 256, 0, stream>>>(xn8, rs, cs, tgt);
    row_term_kernel<<<N_ROWS / 256, 256, 0, stream>>>(rs, cs, tgt, terms);
    loss_kernel<<<1, 256, 0, stream>>>(terms, out);
}

// Round 9
// 114.723 us; speedup vs baseline: 2.0521x; 2.0041x over previous
//
#include <hip/hip_runtime.h>

// NT-Xent loss: z_i, z_j [4096,1024] f32 -> scalar f32 loss.
// loss = mean_i( log(sum_{j != i} exp(2*cos_sim(i,j))) - 2*cos_sim(i, i^1) )
//
// R9: R6 kernel (the last clean fast point: 97us, no scratch) with ONLY the
//     LDS placement map changed. New map: pair two 64-B rows into a 128-B
//     window, XOR chunk position across the window:
//       unit(r,c) = (r>>1)*8 + ((((r&1)<<2)|c) ^ ((r>>1)&7))
//     -> GLDS sources become 16 contiguous 64-B segments per wave (R6 was 64
//     scattered 16-B txns), and frag ds_reads are phase-wise 2-way (free).
//     Everything else (tiles, grid, acc arrays, epilogue) is R6 verbatim.

#define N_ROWS 8192
#define HALF_N 4096
#define DIMK   1024
#define KTILES 16          // 1024 / 64
#define NJC    64          // 128-wide column panels
#define NTILES 1056        // sum_{jc} (jc/2 + 1)
#define LOGIT_SCALE (2.0f / 256.0f)   // /TEMPERATURE, undo 16*16 fp8 pre-scale

typedef float        f32x16 __attribute__((ext_vector_type(16)));
typedef int          i32x8  __attribute__((ext_vector_type(8)));
typedef unsigned int u32x4  __attribute__((ext_vector_type(4)));

// ---------------- fp8 e4m3 (OCP) conversion, RNE, software ------------------
__device__ __forceinline__ unsigned int f32_to_e4m3(float f) {
    unsigned int b = __float_as_uint(f);
    unsigned int s = (b >> 24) & 0x80u;
    float a = fabsf(f);
    if (a < 0.0009765625f) return s;                  // < 2^-10 -> 0
    if (a < 0.015625f) {                              // subnormal: m * 2^-9
        int q = (int)rintf(a * 512.0f);               // 0..8 (8 -> min normal)
        return s | (unsigned int)q;
    }
    if (a >= 464.0f) return s | 0x7Eu;                // clamp to 448
    int e = (int)((b >> 23) & 0xFF) - 127;            // [-6, 8]
    unsigned int man = b & 0x7FFFFFu;
    unsigned int r = man + 0x7FFFFu + ((man >> 20) & 1u);  // RNE to 3 bits
    unsigned int m8 = r >> 20;
    if (m8 == 8u) { m8 = 0u; ++e; if (e > 8) return s | 0x7Eu; }
    return s | ((unsigned int)(e + 7) << 3) | m8;
}

// ---------------- Kernel 1: row L2-normalize, f32 -> fp8*16 ------------------
// one wave per row; 4 waves per block
__global__ __launch_bounds__(256) void norm_rows_kernel(
    const float* __restrict__ z_i, const float* __restrict__ z_j,
    unsigned int* __restrict__ xn8)   // [8192][256] u32 (=1024 fp8)
{
    const int wave = threadIdx.x >> 6, lane = threadIdx.x & 63;
    const int row = blockIdx.x * 4 + wave;
    const float* src = (row < HALF_N) ? (z_i + (size_t)row * DIMK)
                                      : (z_j + (size_t)(row - HALF_N) * DIMK);
    float4 v[4];
    float ss = 0.0f;
    #pragma unroll
    for (int i = 0; i < 4; ++i) {
        v[i] = ((const float4*)src)[i * 64 + lane];
        ss += v[i].x * v[i].x + v[i].y * v[i].y + v[i].z * v[i].z + v[i].w * v[i].w;
    }
    #pragma unroll
    for (int m = 1; m < 64; m <<= 1) ss += __shfl_xor(ss, m, 64);
    const float rn = 16.0f / fmaxf(sqrtf(ss), 1e-8f);   // x16 fp8 pre-scale

    unsigned int* dst = xn8 + (size_t)row * (DIMK / 4);
    #pragma unroll
    for (int i = 0; i < 4; ++i) {
        unsigned int p = f32_to_e4m3(v[i].x * rn)
                       | (f32_to_e4m3(v[i].y * rn) << 8)
                       | (f32_to_e4m3(v[i].z * rn) << 16)
                       | (f32_to_e4m3(v[i].w * rn) << 24);
        dst[i * 64 + lane] = p;
    }
}

// ---- Kernel 2: fused sim-GEMM (MX-fp8 32x32x64) + exp row/col sums ----------
#define BAR() do { asm volatile("" ::: "memory"); \
                   __builtin_amdgcn_s_barrier();  \
                   asm volatile("" ::: "memory"); } while (0)
#define WAITVM0() asm volatile("s_waitcnt vmcnt(0)" ::: "memory")
#define GLDS(gp, lp) __builtin_amdgcn_global_load_lds(                          \
        (const __attribute__((address_space(1))) void*)(gp),                    \
        (__attribute__((address_space(3))) void*)(lp), 16, 0, 0)

// LDS placement: row r has 4x16B chunks; rows are paired into 128-B windows.
// unit(r,c) = (r>>1)*8 + ((((r&1)<<2)|c) ^ ((r>>1)&7)). Bijective. Frag reads
// (32 rows x 2 chunks fixed) hit each bank-quad position exactly 2x per
// 16-lane phase -> conflict-free. GLDS inverse map -> 64-B coalesced source.
__device__ __forceinline__ int unit_of(int r, int c) {
    return ((r >> 1) << 3) + (((((r & 1) << 2) | c)) ^ ((r >> 1) & 7));
}

__global__ __launch_bounds__(256, 2) void simexp_kernel(
    const unsigned char* __restrict__ xn8,
    float* __restrict__ rs,     // [128][N_ROWS] planes: jc*2 + wn
    float* __restrict__ cs,     // [64][N_ROWS]  planes: rt*2 + wm
    float* __restrict__ tgt)    // [N_ROWS]
{
    __shared__ u32x4 Abuf[2][1024];   // 2 x 16 KiB (256 rows x 4 chunks)
    __shared__ u32x4 Bbuf[2][512];    // 2 x  8 KiB (128 rows x 4 chunks)

    // bijective XCD swizzle: 1056 = 8 * 132
    const int orig = blockIdx.x;
    const int bid  = (orig & 7) * 132 + (orig >> 3);

    // decode (rt, jc): tiles ordered jc-major, rt = 0..jc/2
    int rem = bid, jc = 0;
    for (;;) { const int cnt = (jc >> 1) + 1; if (rem < cnt) break; rem -= cnt; ++jc; }
    const int rt = rem;

    const int t = threadIdx.x;
    const int lane = t & 63, wave = t >> 6;
    const int wm = wave >> 1, wn = wave & 1;     // 2x2 wave grid
    const int rowBase = rt * 256, colBase = jc * 128;
    const int l31 = lane & 31, h = lane >> 5;

    f32x16 acc[4][2];
    #pragma unroll
    for (int i = 0; i < 4; ++i)
        #pragma unroll
        for (int j = 0; j < 2; ++j)
            #pragma unroll
            for (int v = 0; v < 16; ++v) acc[i][j][v] = 0.0f;

    // staging: unit u = s_*256 + t (linear LDS dest); inverse map:
    // r2 = u>>3, y = (u&7) ^ (r2&7), row = 2*r2 + (y>>2), chunk = y&3.
#define STAGE_TILE(SLOT, KT) do {                                                \
        _Pragma("unroll")                                                        \
        for (int s_ = 0; s_ < 4; ++s_) {                                         \
            const int u_  = s_ * 256 + t;                                        \
            const int r2_ = u_ >> 3;                                             \
            const int y_  = (u_ & 7) ^ (r2_ & 7);                                \
            const int rl_ = 2 * r2_ + (y_ >> 2);                                 \
            const unsigned char* g = xn8 +                                       \
                (size_t)(rowBase + rl_) * DIMK + (KT) * 64 + (y_ & 3) * 16;      \
            GLDS(g, &Abuf[SLOT][s_ * 256 + wave * 64]);                          \
        }                                                                        \
        _Pragma("unroll")                                                        \
        for (int s_ = 0; s_ < 2; ++s_) {                                         \
            const int u_  = s_ * 256 + t;                                        \
            const int r2_ = u_ >> 3;                                             \
            const int y_  = (u_ & 7) ^ (r2_ & 7);                                \
            const int rl_ = 2 * r2_ + (y_ >> 2);                                 \
            const unsigned char* g = xn8 +                                       \
                (size_t)(colBase + rl_) * DIMK + (KT) * 64 + (y_ & 3) * 16;      \
            GLDS(g, &Bbuf[SLOT][s_ * 256 + wave * 64]);                          \
        }                                                                        \
    } while (0)

    // prologue: tile 0 into slot 0
    STAGE_TILE(0, 0);
    WAITVM0();
    BAR();

    int slot = 0;
    for (int kt = 0; kt < KTILES; ++kt) {
        const bool nx = (kt + 1 < KTILES);
        if (nx) STAGE_TILE(slot ^ 1, kt + 1);

        // fragment reads: lane -> row of frag, k-half h (chunks 2h, 2h+1)
        union Frag { u32x4 q[2]; i32x8 v; };
        i32x8 af[4], bf[2];
        #pragma unroll
        for (int fi = 0; fi < 4; ++fi) {
            const int r = wm * 128 + fi * 32 + l31;
            Frag fa;
            fa.q[0] = Abuf[slot][unit_of(r, 2 * h)];
            fa.q[1] = Abuf[slot][unit_of(r, 2 * h + 1)];
            af[fi] = fa.v;
        }
        #pragma unroll
        for (int cf = 0; cf < 2; ++cf) {
            const int r = wn * 64 + cf * 32 + l31;
            Frag fb;
            fb.q[0] = Bbuf[slot][unit_of(r, 2 * h)];
            fb.q[1] = Bbuf[slot][unit_of(r, 2 * h + 1)];
            bf[cf] = fb.v;
        }

        __builtin_amdgcn_s_setprio(1);
        #pragma unroll
        for (int fi = 0; fi < 4; ++fi)
            #pragma unroll
            for (int cf = 0; cf < 2; ++cf)
                acc[fi][cf] = __builtin_amdgcn_mfma_scale_f32_32x32x64_f8f6f4(
                    af[fi], bf[cf], acc[fi][cf], 0, 0,
                    0, 0x7F7F7F7F, 0, 0x7F7F7F7F);   // fmt=fp8, scales=1.0
        __builtin_amdgcn_s_setprio(0);

        if (nx) WAITVM0();
        BAR();
        slot ^= 1;
    }
#undef STAGE_TILE

    // ---- epilogue ----
    // C/D 32x32 layout (m74/m101): col = lane&31, row = (v&3)+8*(v>>2)+4*(lane>>5)
    float cspart[2] = {0.0f, 0.0f};
    #pragma unroll
    for (int fi = 0; fi < 4; ++fi) {
        float rpart[16];
        #pragma unroll
        for (int v = 0; v < 16; ++v) rpart[v] = 0.0f;
        #pragma unroll
        for (int cf = 0; cf < 2; ++cf) {
            const int gcol = colBase + wn * 64 + cf * 32 + l31;
            #pragma unroll
            for (int v = 0; v < 16; ++v) {
                const int grow = rowBase + wm * 128 + fi * 32
                               + (v & 3) + 8 * (v >> 2) + 4 * h;
                const float tv = acc[fi][cf][v] * LOGIT_SCALE;
                if (gcol == grow + 1 && ((grow & 1) == 0)) {
                    tgt[grow] = tv; tgt[grow + 1] = tv;   // sim symmetric
                }
                const float ev = (gcol > grow) ? __expf(tv) : 0.0f;
                rpart[v] += ev;
                cspart[cf] += ev;
            }
        }
        // row sums: reduce over the 32 columns (lanes sharing l>>5)
        #pragma unroll
        for (int m = 1; m < 32; m <<= 1) {
            #pragma unroll
            for (int v = 0; v < 16; ++v) rpart[v] += __shfl_xor(rpart[v], m, 64);
        }
        if (l31 == 0) {
            float* dst = rs + (size_t)(jc * 2 + wn) * N_ROWS;
            #pragma unroll
            for (int v = 0; v < 16; ++v)
                dst[rowBase + wm * 128 + fi * 32 + (v & 3) + 8 * (v >> 2) + 4 * h]
                    = rpart[v];
        }
    }
    // column sums (mirror): combine lane halves, lanes 0-31 write
    #pragma unroll
    for (int cf = 0; cf < 2; ++cf) {
        cspart[cf] += __shfl_xor(cspart[cf], 32, 64);
        if (lane < 32)
            cs[(size_t)(rt * 2 + wm) * N_ROWS + colBase + wn * 64 + cf * 32 + l31]
                = cspart[cf];
    }
}

// ------------- Kernel 3: per-row LSE - target logit --------------------------
// row x: rs planes jc*2+{0,1} for jc >= 2*(x>>8); cs planes rt*2+{0,1} for
// rt <= (x>>7)/2  (exactly the tiles that exist for this row/col).
__global__ __launch_bounds__(256) void row_term_kernel(
    const float* __restrict__ rs, const float* __restrict__ cs,
    const float* __restrict__ tgt, float* __restrict__ terms)
{
    const int row = blockIdx.x * 256 + threadIdx.x;
    const int P = row >> 8, jcx = row >> 7;
    float s = 0.0f;
    for (int jc = 2 * P; jc < NJC; ++jc) {
        const float* b = rs + (size_t)(jc * 2) * N_ROWS + row;
        s += b[0] + b[N_ROWS];
    }
    for (int rt = 0; rt <= (jcx >> 1); ++rt) {
        const float* b = cs + (size_t)(rt * 2) * N_ROWS + row;
        s += b[0] + b[N_ROWS];
    }
    terms[row] = logf(s) - tgt[row];
}

// ------------- Kernel 4: mean over rows --------------------------------------
__global__ __launch_bounds__(256) void loss_kernel(
    const float* __restrict__ terms, float* __restrict__ out)
{
    const int t = threadIdx.x;
    float s = 0.0f;
    for (int i = t; i < N_ROWS; i += 256) s += terms[i];
    #pragma unroll
    for (int m = 1; m < 64; m <<= 1) s += __shfl_xor(s, m, 64);
    __shared__ float red[4];
    if ((t & 63) == 0) red[t >> 6] = s;
    __syncthreads();
    if (t == 0) out[0] = (red[0] + red[1] + red[2] + red[3]) * (1.0f / N_ROWS);
}

extern "C" void kernel_launch(void* const* d_in, const int* in_sizes, int n_in,
                              void* d_out, int out_size, void* d_ws, size_t ws_size,
                              hipStream_t stream)
{
    const float* z_i = (const float*)d_in[0];
    const float* z_j = (const float*)d_in[1];
    float* out = (float*)d_out;

    // workspace layout
    unsigned char* xn8 = (unsigned char*)d_ws;                        // 8 MiB fp8
    float* rs    = (float*)(xn8 + (size_t)N_ROWS * DIMK);             // 4 MiB
    float* cs    = rs + (size_t)128 * N_ROWS;                         // 2 MiB
    float* tgt   = cs + (size_t)64 * N_ROWS;                          // 32 KiB
    float* terms = tgt + N_ROWS;                                      // 32 KiB

    norm_rows_kernel<<<N_ROWS / 4, 256, 0, stream>>>(z_i, z_j, (unsigned int*)xn8);
    simexp_kernel<<<NTILES, 256, 0, stream>>>(xn8, rs, cs, tgt);
    row_term_kernel<<<N_ROWS / 256, 256, 0, stream>>>(rs, cs, tgt, terms);
    loss_kernel<<<1, 256, 0, stream>>>(terms, out);
}